// Round 8
// baseline (225.750 us; speedup 1.0000x reference)
//
#include <hip/hip_runtime.h>
#include <math.h>

#define T_DIM 1024
#define B_DIM 4
#define H_DIM 1024
#define NHEAD 16
#define DHEAD 64
#define NROWS (T_DIM * B_DIM)   // 4096
#define LPOS  (2 * T_DIM - 1)   // 2047
#define QS    (3 * H_DIM)

typedef __attribute__((ext_vector_type(8))) short bfrag;   // 8 bf16
typedef __attribute__((ext_vector_type(4))) short sh4;
typedef __attribute__((ext_vector_type(4))) float facc;

static __device__ __forceinline__ short f2bf(float f) {
    unsigned u = __builtin_bit_cast(unsigned, f);
    u = (u + 0x7FFFu + ((u >> 16) & 1u)) >> 16;   // RNE
    return (short)u;
}
static __device__ __forceinline__ float bf2f(short s) {
    unsigned u = ((unsigned)(unsigned short)s) << 16;
    return __builtin_bit_cast(float, u);
}

#define GLD16(g, l) __builtin_amdgcn_global_load_lds( \
    (const __attribute__((address_space(1))) void*)(g), \
    (__attribute__((address_space(3))) void*)(l), 16, 0, 0)

// ---------------- f32 -> bf16 convert ----------------
__global__ __launch_bounds__(256) void cvt_kernel(const float* __restrict__ in,
                                                  short* __restrict__ out, int n) {
    int i = (blockIdx.x * 256 + threadIdx.x) * 8;
    if (i >= n) return;
    float4 a = *(const float4*)(in + i);
    float4 b = *(const float4*)(in + i + 4);
    bfrag f;
    f[0] = f2bf(a.x); f[1] = f2bf(a.y); f[2] = f2bf(a.z); f[3] = f2bf(a.w);
    f[4] = f2bf(b.x); f[5] = f2bf(b.y); f[6] = f2bf(b.z); f[7] = f2bf(b.w);
    *(bfrag*)(out + i) = f;
}

// ---------------- LayerNorm: f32 in, bf16 out ----------------
__global__ __launch_bounds__(256) void ln_kernel(const float* __restrict__ x,
                                                 const float* __restrict__ w,
                                                 const float* __restrict__ b,
                                                 short* __restrict__ y) {
    int row = blockIdx.x;
    const float* xr = x + (size_t)row * H_DIM;
    short* yr = y + (size_t)row * H_DIM;
    int tid = threadIdx.x;

    float4 v = reinterpret_cast<const float4*>(xr)[tid];
    float s  = v.x + v.y + v.z + v.w;
    float sq = v.x * v.x + v.y * v.y + v.z * v.z + v.w * v.w;

    #pragma unroll
    for (int m = 32; m; m >>= 1) {
        s  += __shfl_xor(s, m);
        sq += __shfl_xor(sq, m);
    }
    __shared__ float red0[4], red1[4];
    int wave = tid >> 6, lane = tid & 63;
    if (lane == 0) { red0[wave] = s; red1[wave] = sq; }
    __syncthreads();
    float tot   = red0[0] + red0[1] + red0[2] + red0[3];
    float totsq = red1[0] + red1[1] + red1[2] + red1[3];
    float mean = tot * (1.0f / H_DIM);
    float var  = totsq * (1.0f / H_DIM) - mean * mean;
    float rstd = rsqrtf(var + 1e-5f);

    float4 wv = reinterpret_cast<const float4*>(w)[tid];
    float4 bv = reinterpret_cast<const float4*>(b)[tid];
    sh4 o;
    o[0] = f2bf((v.x - mean) * rstd * wv.x + bv.x);
    o[1] = f2bf((v.y - mean) * rstd * wv.y + bv.y);
    o[2] = f2bf((v.z - mean) * rstd * wv.z + bv.z);
    o[3] = f2bf((v.w - mean) * rstd * wv.w + bv.w);
    reinterpret_cast<sh4*>(yr)[tid] = o;
}

// -------- bf16 MFMA GEMM: C[M,N] = A[M,K] @ B[N,K]^T + bias --------
// MODE 0: f32 out. MODE 1: bf16 out. MODE 2: bf16 out + transposed side-write
// of columns >= 2H into vT[b][hd][t] (b = gr&3 == rg, t = gr>>2).
template<int MODE>
__global__ __launch_bounds__(256) void gemm_mfma(const short* __restrict__ A,
                                                 const short* __restrict__ B,
                                                 const float* __restrict__ bias,
                                                 void* __restrict__ Cv,
                                                 short* __restrict__ vT,
                                                 int M, int N, int K) {
    __shared__ short As[128][64];
    __shared__ short Bs[128][64];
    const int tid = threadIdx.x;
    const int w4 = tid >> 6, l = tid & 63;
    const int lc = l & 15, lg = l >> 4;
    const int wr = w4 >> 1, wc = w4 & 1;
    const int row0 = blockIdx.y * 128, col0 = blockIdx.x * 128;
    const int srow = l >> 3;
    const int schunk = ((l & 7) ^ srow) * 8;
    const int Mm1 = M - 1;

    facc acc[4][4];
    #pragma unroll
    for (int i = 0; i < 4; ++i)
        #pragma unroll
        for (int j = 0; j < 4; ++j) acc[i][j] = (facc){0.f, 0.f, 0.f, 0.f};

    for (int k0 = 0; k0 < K; k0 += 64) {
        #pragma unroll
        for (int p = 0; p < 4; ++p) {
            int rA = p * 32 + w4 * 8 + srow;
            int ga = row0 + rA; if (ga > Mm1) ga = Mm1;
            GLD16(A + (size_t)ga * K + k0 + schunk,
                  (char*)As + p * 4096 + w4 * 1024);
            GLD16(B + (size_t)(col0 + rA) * K + k0 + schunk,
                  (char*)Bs + p * 4096 + w4 * 1024);
        }
        __syncthreads();

        bfrag af[4][2], bfr[4][2];
        #pragma unroll
        for (int fr = 0; fr < 4; ++fr) {
            const int ra = wr * 64 + fr * 16 + lc;
            #pragma unroll
            for (int ks = 0; ks < 2; ++ks)
                af[fr][ks] = *(const bfrag*)&As[ra][(((ks * 4 + lg) ^ (ra & 7)) << 3)];
        }
        #pragma unroll
        for (int fc = 0; fc < 4; ++fc) {
            const int rb = wc * 64 + fc * 16 + lc;
            #pragma unroll
            for (int ks = 0; ks < 2; ++ks)
                bfr[fc][ks] = *(const bfrag*)&Bs[rb][(((ks * 4 + lg) ^ (rb & 7)) << 3)];
        }
        #pragma unroll
        for (int fr = 0; fr < 4; ++fr)
            #pragma unroll
            for (int fc = 0; fc < 4; ++fc)
                #pragma unroll
                for (int ks = 0; ks < 2; ++ks)
                    acc[fr][fc] = __builtin_amdgcn_mfma_f32_16x16x32_bf16(
                        af[fr][ks], bfr[fc][ks], acc[fr][fc], 0, 0, 0);
        __syncthreads();
    }

    #pragma unroll
    for (int fc = 0; fc < 4; ++fc) {
        const int gc = col0 + wc * 64 + fc * 16 + lc;
        const float bv = bias ? bias[gc] : 0.f;
        #pragma unroll
        for (int fr = 0; fr < 4; ++fr) {
            #pragma unroll
            for (int rg = 0; rg < 4; ++rg) {
                const int gr = row0 + wr * 64 + fr * 16 + lg * 4 + rg;
                if (gr < M) {
                    float o = acc[fr][fc][rg] + bv;
                    if constexpr (MODE == 0) {
                        ((float*)Cv)[(size_t)gr * N + gc] = o;
                    } else {
                        short ob = f2bf(o);
                        ((short*)Cv)[(size_t)gr * N + gc] = ob;
                        if constexpr (MODE == 2) {
                            if (gc >= 2 * H_DIM) {
                                const int t = gr >> 2, bb = gr & 3;   // bb == rg
                                vT[(((size_t)(bb * H_DIM + (gc - 2 * H_DIM))) << 10) + t] = ob;
                            }
                        }
                    }
                }
            }
        }
    }
}

// --------------------- Flash MFMA attention (bf16 in/out) -----------------
// score2[i,j] = (qw[i]·k[j] + qr[i]·r[j-i+1023]) * log2e/8  (exp2 domain)
// K/V double-buffered; GLD16(t+1) issued between AC/BD and softmax/PV so HBM
// latency hides under compute. BDs/Ps padded for conflict-free lg-groups.
// Defer-max (T13, THR=8 in log2 domain) skips O-rescale on stable tiles.
__global__ __launch_bounds__(256) void attn_mfma(const short* __restrict__ qkv,
                                                 const short* __restrict__ r,
                                                 const short* __restrict__ vt,
                                                 const float* __restrict__ rwb,
                                                 const float* __restrict__ rrb,
                                                 short* __restrict__ out) {
    __shared__ short Ks[2][64][64];
    __shared__ short Vt[2][64][64];
    __shared__ short Rs[128][64];
    __shared__ short BDs[4][16][84];   // pitch 42 dwords: lg banks 0/8/16/24
    __shared__ short Ps[4][16][76];    // pitch 38 dwords: lg banks 0/24/16/8

    const int i0  = blockIdx.x * 64;
    const int b   = blockIdx.y >> 4;
    const int n   = blockIdx.y & 15;
    const int tid = threadIdx.x;
    const int w   = tid >> 6;
    const int l   = tid & 63;
    const int lg  = l >> 4;
    const int lc  = l & 15;
    const int hoff = n * DHEAD;

    // staging source decode (per lane)
    const int srow8 = l >> 3;                        // row within 8-row chunk
    const int sc8   = ((l & 7) ^ srow8) * 8;         // inverse-swizzled col chunk

    // ---- Q fragments (scale includes log2e for exp2-domain softmax) ----
    bfrag qw[2], qr[2];
    {
        const int row = i0 + 16 * w + lc;
        const short* qrow = qkv + (size_t)(row * B_DIM + b) * QS + hoff;
        #pragma unroll
        for (int ks = 0; ks < 2; ++ks) {
            const int d0 = ks * 32 + lg * 8;
            bfrag qv = *(const bfrag*)(qrow + d0);
            float4 wa = *(const float4*)(rwb + hoff + d0);
            float4 wb = *(const float4*)(rwb + hoff + d0 + 4);
            float4 ra = *(const float4*)(rrb + hoff + d0);
            float4 rb = *(const float4*)(rrb + hoff + d0 + 4);
            const float sc = 0.125f * 1.44269504f;
            float wf[8] = {wa.x, wa.y, wa.z, wa.w, wb.x, wb.y, wb.z, wb.w};
            float rf[8] = {ra.x, ra.y, ra.z, ra.w, rb.x, rb.y, rb.z, rb.w};
            bfrag fw, fr;
            #pragma unroll
            for (int e = 0; e < 8; ++e) {
                float qf = bf2f(qv[e]);
                fw[e] = f2bf((qf + wf[e]) * sc);
                fr[e] = f2bf((qf + rf[e]) * sc);
            }
            qw[ks] = fw; qr[ks] = fr;
        }
    }

    facc ofr[4];
    #pragma unroll
    for (int d = 0; d < 4; ++d) ofr[d] = (facc){0.f, 0.f, 0.f, 0.f};
    float mrow[4] = {-1e30f, -1e30f, -1e30f, -1e30f};
    float lrow[4] = {0.f, 0.f, 0.f, 0.f};
    const int wbase = 16 * (3 - w);

    // ---- staging helper ----
    auto stage = [&](int jt, int nb) {
        const int j0 = jt * 64;
        const int l_min = j0 + 960 - i0;
        #pragma unroll
        for (int p = 0; p < 2; ++p) {
            const int c8 = w * 2 + p;
            const int j = c8 * 8 + srow8;
            GLD16(qkv + (size_t)((j0 + j) * B_DIM + b) * QS + H_DIM + hoff + sc8,
                  (char*)Ks[nb] + c8 * 1024);
        }
        #pragma unroll
        for (int p = 0; p < 4; ++p) {
            const int c16 = w * 4 + p;
            int lrw = l_min + c16 * 8 + srow8; if (lrw > 2046) lrw = 2046;
            GLD16(r + (size_t)lrw * H_DIM + hoff + sc8,
                  (char*)Rs + c16 * 1024);
        }
        #pragma unroll
        for (int p = 0; p < 2; ++p) {
            const int c8 = w * 2 + p;
            const int dd = c8 * 8 + srow8;
            GLD16(vt + (((size_t)(b * H_DIM + hoff + dd)) << 10) + j0 + sc8,
                  (char*)Vt[nb] + c8 * 1024);
        }
    };

    stage(0, 0);
    __syncthreads();
    int cur = 0;

    for (int jt = 0; jt < 16; ++jt) {
        // ---- AC: S = Qw · K^T ----
        __builtin_amdgcn_s_setprio(1);
        facc sfr[4];
        #pragma unroll
        for (int js = 0; js < 4; ++js) {
            sfr[js] = (facc){0.f, 0.f, 0.f, 0.f};
            const int jrow = js * 16 + lc;
            #pragma unroll
            for (int ks = 0; ks < 2; ++ks) {
                const int ch = (ks * 4 + lg) ^ (jrow & 7);
                bfrag bf = *(const bfrag*)&Ks[cur][jrow][ch << 3];
                sfr[js] = __builtin_amdgcn_mfma_f32_16x16x32_bf16(qw[ks], bf, sfr[js], 0, 0, 0);
            }
        }
        // ---- BD: wave-local 16x80 block of Qr · r^T -> BDs (bf16) ----
        #pragma unroll
        for (int ls = 0; ls < 5; ++ls) {
            facc bd = (facc){0.f, 0.f, 0.f, 0.f};
            const int rrow = wbase + ls * 16 + lc;
            #pragma unroll
            for (int ks = 0; ks < 2; ++ks) {
                const int ch = (ks * 4 + lg) ^ (rrow & 7);
                bfrag bf = *(const bfrag*)&Rs[rrow][ch << 3];
                bd = __builtin_amdgcn_mfma_f32_16x16x32_bf16(qr[ks], bf, bd, 0, 0, 0);
            }
            #pragma unroll
            for (int rg = 0; rg < 4; ++rg)
                BDs[w][lg * 4 + rg][ls * 16 + lc] = f2bf(bd[rg]);
        }
        __builtin_amdgcn_s_setprio(0);

        // all waves done reading Rs (and Ks[cur] not touched by next stage)
        __syncthreads();

        // ---- issue next tile's loads; they fly under softmax+PV ----
        if (jt < 15) stage(jt + 1, cur ^ 1);

        // ---- rel-shift gather + online softmax (exp2 domain) ----
        float pvv[4][4], tmax[4] = {-1e30f, -1e30f, -1e30f, -1e30f};
        #pragma unroll
        for (int js = 0; js < 4; ++js)
            #pragma unroll
            for (int rg = 0; rg < 4; ++rg) {
                const int irow = lg * 4 + rg;
                float v = sfr[js][rg] + bf2f(BDs[w][irow][js * 16 + lc - irow + 15]);
                pvv[js][rg] = v;
                tmax[rg] = fmaxf(tmax[rg], v);
            }
        #pragma unroll
        for (int m = 1; m < 16; m <<= 1)
            #pragma unroll
            for (int rg = 0; rg < 4; ++rg)
                tmax[rg] = fmaxf(tmax[rg], __shfl_xor(tmax[rg], m));

        // defer-max: only rescale when a row's max grew by > 8 (P <= 2^8)
        bool ok = true;
        #pragma unroll
        for (int rg = 0; rg < 4; ++rg) ok &= (tmax[rg] <= mrow[rg] + 8.0f);
        if (!__all(ok)) {
            #pragma unroll
            for (int rg = 0; rg < 4; ++rg) {
                float mnew = fmaxf(mrow[rg], tmax[rg]);
                float sf = exp2f(mrow[rg] - mnew);
                mrow[rg] = mnew;
                lrow[rg] *= sf;
                #pragma unroll
                for (int d = 0; d < 4; ++d) ofr[d][rg] *= sf;
            }
        }

        float rsum[4] = {0.f, 0.f, 0.f, 0.f};
        #pragma unroll
        for (int js = 0; js < 4; ++js)
            #pragma unroll
            for (int rg = 0; rg < 4; ++rg) {
                float p = exp2f(pvv[js][rg] - mrow[rg]);
                rsum[rg] += p;
                Ps[w][lg * 4 + rg][js * 16 + lc] = f2bf(p);
            }
        #pragma unroll
        for (int m = 1; m < 16; m <<= 1)
            #pragma unroll
            for (int rg = 0; rg < 4; ++rg)
                rsum[rg] += __shfl_xor(rsum[rg], m);
        #pragma unroll
        for (int rg = 0; rg < 4; ++rg)
            lrow[rg] += rsum[rg];

        // ---- PV: O += P · V ----
        bfrag pf[2];
        #pragma unroll
        for (int ks = 0; ks < 2; ++ks)
            pf[ks] = *(const bfrag*)&Ps[w][lc][ks * 32 + lg * 8];
        __builtin_amdgcn_s_setprio(1);
        #pragma unroll
        for (int d = 0; d < 4; ++d) {
            #pragma unroll
            for (int ks = 0; ks < 2; ++ks) {
                const int vr = d * 16 + lc;
                const int ch = (ks * 4 + lg) ^ (vr & 7);
                bfrag vf = *(const bfrag*)&Vt[cur][vr][ch << 3];
                ofr[d] = __builtin_amdgcn_mfma_f32_16x16x32_bf16(pf[ks], vf, ofr[d], 0, 0, 0);
            }
        }
        __builtin_amdgcn_s_setprio(0);

        // drains the t+1 loads; syncs Rs for next BD
        __syncthreads();
        cur ^= 1;
    }

    // ---- write O ----
    #pragma unroll
    for (int rg = 0; rg < 4; ++rg) {
        const float inv = 1.0f / lrow[rg];
        const int row = i0 + 16 * w + lg * 4 + rg;
        short* orow = out + (size_t)(row * B_DIM + b) * H_DIM + hoff;
        #pragma unroll
        for (int d = 0; d < 4; ++d)
            orow[d * 16 + lc] = f2bf(ofr[d][rg] * inv);
    }
}

extern "C" void kernel_launch(void* const* d_in, const int* in_sizes, int n_in,
                              void* d_out, int out_size, void* d_ws, size_t ws_size,
                              hipStream_t stream) {
    const float* x          = (const float*)d_in[0];
    const float* pos        = (const float*)d_in[1];
    const float* ln_w       = (const float*)d_in[3];
    const float* ln_b       = (const float*)d_in[4];
    const float* in_proj_w  = (const float*)d_in[5];
    const float* in_proj_b  = (const float*)d_in[6];
    const float* pos_proj_w = (const float*)d_in[7];
    const float* r_w_bias   = (const float*)d_in[8];
    const float* r_r_bias   = (const float*)d_in[9];
    const float* out_proj_w = (const float*)d_in[10];
    const float* out_proj_b = (const float*)d_in[11];
    float* out = (float*)d_out;

    short* qn   = (short*)d_ws;                      // [4096,1024] (reused as attn_out)
    short* qkv  = qn + (size_t)NROWS * H_DIM;        // [4096,3072]
    short* rbuf = qkv + (size_t)NROWS * QS;          // [2048,1024]
    short* wi   = rbuf + (size_t)2048 * H_DIM;
    short* wp   = wi + (size_t)QS * H_DIM;
    short* wo   = wp + (size_t)H_DIM * H_DIM;
    short* posb = wo + (size_t)H_DIM * H_DIM;        // [2048,1024]
    short* vT   = posb + (size_t)2048 * H_DIM;       // [4][1024][1024] transposed V

    const int n_pos = LPOS * H_DIM;
    cvt_kernel<<<(n_pos + 2047) / 2048, 256, 0, stream>>>(pos, posb, n_pos);
    cvt_kernel<<<(QS * H_DIM + 2047) / 2048, 256, 0, stream>>>(in_proj_w, wi, QS * H_DIM);
    cvt_kernel<<<(H_DIM * H_DIM + 2047) / 2048, 256, 0, stream>>>(pos_proj_w, wp, H_DIM * H_DIM);
    cvt_kernel<<<(H_DIM * H_DIM + 2047) / 2048, 256, 0, stream>>>(out_proj_w, wo, H_DIM * H_DIM);

    ln_kernel<<<NROWS, 256, 0, stream>>>(x, ln_w, ln_b, qn);

    gemm_mfma<2><<<dim3(QS / 128, NROWS / 128), 256, 0, stream>>>(
        qn, wi, in_proj_b, qkv, vT, NROWS, QS, H_DIM);

    gemm_mfma<1><<<dim3(H_DIM / 128, (LPOS + 127) / 128), 256, 0, stream>>>(
        posb, wp, nullptr, rbuf, nullptr, LPOS, H_DIM, H_DIM);

    attn_mfma<<<dim3(T_DIM / 64, B_DIM * NHEAD), 256, 0, stream>>>(
        qkv, rbuf, vT, r_w_bias, r_r_bias, qn);

    gemm_mfma<0><<<dim3(H_DIM / 128, NROWS / 128), 256, 0, stream>>>(
        qn, wo, out_proj_b, out, nullptr, NROWS, H_DIM, H_DIM);
}